// Round 9
// baseline (126.701 us; speedup 1.0000x reference)
//
#include <hip/hip_runtime.h>
#include <math.h>

// knnLoss: B=4, N=8192, k=3. Brute-force 3-NN, two kernels.
// R9: double occupancy (16 -> 32 waves/CU) + deferred single fixup.
//   - 1024 blocks x 512 threads (NQ=8 slices x NG=32 groups x 4 batch),
//     4 blocks/CU. __launch_bounds__(512,8) pins VGPR<=64 (R8 measured 60).
//   - Wave w stages its own 128-target slot (16 octets, 28-float stride) and
//     reads only it: zero barriers in the main body.
//   - Packed chains carry 7-bit block-octet id (wave*16+o). ONE barrier, then
//     thread tid<256 merges its source's 8 packed chains (LDS) and does just
//     3 octet_fix per source per block (vs per-wave in R8: 4x less fixup).
//     Exactness: top-3 value's octet is a top-3 octet-min over the block's
//     128 octets (containment); fixup recomputes exact values, so the 2^-16
//     packing perturbation affects selection only (ties).
//   - Hot loop fully unrolled: ds_read offsets fold to immediates.
//   - knn_merge: 24 partials/source, proven 128x256 shape + ticket finale.
#define BATCH 4
#define NPTS 8192
#define NSRC 32768            // BATCH * NPTS
#define WAVES 8
#define NQ 8                  // target slices of 1024 per batch
#define NG 32                 // source groups of 256 per batch
#define SPB 256               // sources per block (64 lanes x 4)
#define NOCTW 16              // octets per wave slot (128 targets)
#define OCTF 28               // floats per octet (24 data + 4 pad) = 112 B
#define SLOTF (NOCTW * OCTF)  // 448 floats per wave slot
#define CHBASE (WAVES * SLOTF)      // 3584 floats: chain area start
#define LDSF (CHBASE + SPB * 24)    // 3584 + 6144 = 9728 floats = 38912 B
#define MERGE_BLOCKS 128

typedef __attribute__((ext_vector_type(2))) float f2;

__device__ __forceinline__ float min3f(float a, float b, float c) {
    float d;
    asm("v_min3_f32 %0, %1, %2, %3" : "=v"(d) : "v"(a), "v"(b), "v"(c));
    return d;
}

// Branchless insert into sorted ascending triple; 4 ops via med3.
__device__ __forceinline__ void insert3(float d, float& a0, float& a1, float& a2) {
    float h = fmaxf(a1, d);
    float m = __builtin_amdgcn_fmed3f(a0, a1, d);
    a2 = fminf(a2, h);
    a1 = m;
    a0 = fminf(a0, d);
}

// Merge two sorted-ascending triples -> the sorted 3 smallest of the union.
__device__ __forceinline__ void merge33(float a0, float a1, float a2,
                                        float& b0, float& b1, float& b2) {
    float s0 = fminf(a0, b0);
    float h  = fmaxf(a0, b0);
    float m  = fminf(a1, b1);
    float mm = fminf(a2, b2);
    b1 = fminf(h, m);
    b2 = __builtin_amdgcn_fmed3f(h, m, mm);
    b0 = s0;
}

// Exact recompute of one octet (6 float4s, w rebuilt) -> insert into chain.
__device__ __forceinline__ void octet_fix(const float4* ob, f2 nx, f2 ny, f2 nz,
                                          float& c0, float& c1, float& c2) {
    float4 X0 = ob[0], X1 = ob[1], Y0 = ob[2], Y1 = ob[3], Z0 = ob[4], Z1 = ob[5];
    f2 xs0 = (f2){X0.x, X0.y}, xs1 = (f2){X0.z, X0.w};
    f2 xs2 = (f2){X1.x, X1.y}, xs3 = (f2){X1.z, X1.w};
    f2 ys0 = (f2){Y0.x, Y0.y}, ys1 = (f2){Y0.z, Y0.w};
    f2 ys2 = (f2){Y1.x, Y1.y}, ys3 = (f2){Y1.z, Y1.w};
    f2 zs0 = (f2){Z0.x, Z0.y}, zs1 = (f2){Z0.z, Z0.w};
    f2 zs2 = (f2){Z1.x, Z1.y}, zs3 = (f2){Z1.z, Z1.w};
    f2 w0 = zs0 * zs0; w0 = __builtin_elementwise_fma(ys0, ys0, w0);
    w0 = __builtin_elementwise_fma(xs0, xs0, w0);
    f2 w1 = zs1 * zs1; w1 = __builtin_elementwise_fma(ys1, ys1, w1);
    w1 = __builtin_elementwise_fma(xs1, xs1, w1);
    f2 w2 = zs2 * zs2; w2 = __builtin_elementwise_fma(ys2, ys2, w2);
    w2 = __builtin_elementwise_fma(xs2, xs2, w2);
    f2 w3 = zs3 * zs3; w3 = __builtin_elementwise_fma(ys3, ys3, w3);
    w3 = __builtin_elementwise_fma(xs3, xs3, w3);
    f2 pa = __builtin_elementwise_fma(zs0, nz, w0);
    pa = __builtin_elementwise_fma(ys0, ny, pa);
    pa = __builtin_elementwise_fma(xs0, nx, pa);
    f2 pb = __builtin_elementwise_fma(zs1, nz, w1);
    pb = __builtin_elementwise_fma(ys1, ny, pb);
    pb = __builtin_elementwise_fma(xs1, nx, pb);
    f2 pc = __builtin_elementwise_fma(zs2, nz, w2);
    pc = __builtin_elementwise_fma(ys2, ny, pc);
    pc = __builtin_elementwise_fma(xs2, nx, pc);
    f2 pd = __builtin_elementwise_fma(zs3, nz, w3);
    pd = __builtin_elementwise_fma(ys3, ny, pd);
    pd = __builtin_elementwise_fma(xs3, nx, pd);
    insert3(pa.x, c0, c1, c2);
    insert3(pa.y, c0, c1, c2);
    insert3(pb.x, c0, c1, c2);
    insert3(pb.y, c0, c1, c2);
    insert3(pc.x, c0, c1, c2);
    insert3(pc.y, c0, c1, c2);
    insert3(pd.x, c0, c1, c2);
    insert3(pd.y, c0, c1, c2);
}

__global__ __launch_bounds__(512, 8) void knn_partial(const float* __restrict__ src,
                                                      const float* __restrict__ tgt,
                                                      float* __restrict__ part) {
    __shared__ float tsf[LDSF];  // 38912 B -> 4 blocks/CU
    const int tid = threadIdx.x;
    const int lane = tid & 63, wave = tid >> 6;
    const int Q = blockIdx.x, G = blockIdx.y, b = blockIdx.z;

    // ---- Stage: lane l loads targets 2l,2l+1 of this wave's 128-target slot
    // (24B = 3 float2, 8B-aligned), writes into octet o=l>>2 at pair k.
    {
        const float2* t2 = (const float2*)(tgt +
            ((size_t)b * NPTS + Q * 1024 + wave * 128 + 2 * lane) * 3);
        float2 A = t2[0], Bv = t2[1], C = t2[2];
        float x0 = A.x, y0 = A.y, z0 = Bv.x;
        float x1 = Bv.y, y1 = C.x, z1 = C.y;
        if (!(x0 != 0.f || y0 != 0.f || z0 != 0.f)) { x0 = 1e12f; y0 = 1e12f; z0 = 1e12f; }
        if (!(x1 != 0.f || y1 != 0.f || z1 != 0.f)) { x1 = 1e12f; y1 = 1e12f; z1 = 1e12f; }
        int o = lane >> 2, k = (lane & 3) * 2;
        float* bp = tsf + wave * SLOTF + o * OCTF + k;
        *(float2*)(bp)      = make_float2(x0, x1);
        *(float2*)(bp + 8)  = make_float2(y0, y1);
        *(float2*)(bp + 16) = make_float2(z0, z1);
    }
    // No barrier: each wave reads only the slot it wrote (lgkmcnt orders).

    // ---- Source precompute: lane owns 4 sources G*256 + s*64 + lane.
    f2 nx[4], ny[4], nz[4];
    #pragma unroll
    for (int s = 0; s < 4; ++s) {
        const float* sp = src + ((size_t)b * NPTS + G * 256 + s * 64 + lane) * 3;
        float ax = sp[0], ay = sp[1], az = sp[2];
        nx[s] = (f2){-2.f * ax, -2.f * ax};
        ny[s] = (f2){-2.f * ay, -2.f * ay};
        nz[s] = (f2){-2.f * az, -2.f * az};
    }

    // ---- Hot loop: 16 octets, 6 broadcast b128 reads each, 4 sources/lane.
    float q0[4], q1[4], q2c[4];
    #pragma unroll
    for (int s = 0; s < 4; ++s) { q0[s] = q1[s] = q2c[s] = 3e38f; }

    const float4* tsv = ((const float4*)tsf) + wave * (SLOTF / 4);
    const unsigned woct = (unsigned)(wave << 4);
    #pragma unroll
    for (int o = 0; o < NOCTW; ++o) {
        float4 X0 = tsv[7 * o + 0], X1 = tsv[7 * o + 1];
        float4 Y0 = tsv[7 * o + 2], Y1 = tsv[7 * o + 3];
        float4 Z0 = tsv[7 * o + 4], Z1 = tsv[7 * o + 5];
        f2 xs0 = (f2){X0.x, X0.y}, xs1 = (f2){X0.z, X0.w};
        f2 xs2 = (f2){X1.x, X1.y}, xs3 = (f2){X1.z, X1.w};
        f2 ys0 = (f2){Y0.x, Y0.y}, ys1 = (f2){Y0.z, Y0.w};
        f2 ys2 = (f2){Y1.x, Y1.y}, ys3 = (f2){Y1.z, Y1.w};
        f2 zs0 = (f2){Z0.x, Z0.y}, zs1 = (f2){Z0.z, Z0.w};
        f2 zs2 = (f2){Z1.x, Z1.y}, zs3 = (f2){Z1.z, Z1.w};
        // w = |t|^2 once per octet, amortized over 4 sources.
        f2 w0 = zs0 * zs0; w0 = __builtin_elementwise_fma(ys0, ys0, w0);
        w0 = __builtin_elementwise_fma(xs0, xs0, w0);
        f2 w1 = zs1 * zs1; w1 = __builtin_elementwise_fma(ys1, ys1, w1);
        w1 = __builtin_elementwise_fma(xs1, xs1, w1);
        f2 w2 = zs2 * zs2; w2 = __builtin_elementwise_fma(ys2, ys2, w2);
        w2 = __builtin_elementwise_fma(xs2, xs2, w2);
        f2 w3 = zs3 * zs3; w3 = __builtin_elementwise_fma(ys3, ys3, w3);
        w3 = __builtin_elementwise_fma(xs3, xs3, w3);
        #pragma unroll
        for (int s = 0; s < 4; ++s) {
            f2 pa = __builtin_elementwise_fma(zs0, nz[s], w0);
            pa = __builtin_elementwise_fma(ys0, ny[s], pa);
            pa = __builtin_elementwise_fma(xs0, nx[s], pa);
            f2 pb = __builtin_elementwise_fma(zs1, nz[s], w1);
            pb = __builtin_elementwise_fma(ys1, ny[s], pb);
            pb = __builtin_elementwise_fma(xs1, nx[s], pb);
            f2 pc = __builtin_elementwise_fma(zs2, nz[s], w2);
            pc = __builtin_elementwise_fma(ys2, ny[s], pc);
            pc = __builtin_elementwise_fma(xs2, nx[s], pc);
            f2 pd = __builtin_elementwise_fma(zs3, nz[s], w3);
            pd = __builtin_elementwise_fma(ys3, ny[s], pd);
            pd = __builtin_elementwise_fma(xs3, nx[s], pd);
            float m1 = min3f(pa.x, pa.y, pb.x);
            float m2 = min3f(pb.y, pc.x, pc.y);
            float m3 = min3f(pd.x, pd.y, m1);
            float m4 = fminf(m2, m3);
            unsigned u = (__float_as_uint(m4) & 0xFFFFFF80u) | (woct + (unsigned)o);
            insert3(__uint_as_float(u), q0[s], q1[s], q2c[s]);
        }
    }

    // ---- Publish packed chains: chains[src_local][wave*3 .. +2].
    #pragma unroll
    for (int s = 0; s < 4; ++s) {
        int ci = CHBASE + (s * 64 + lane) * 24 + wave * 3;
        tsf[ci] = q0[s]; tsf[ci + 1] = q1[s]; tsf[ci + 2] = q2c[s];
    }
    __syncthreads();  // chains written; slots stay intact below

    // ---- tid<256: merge 8 packed chains for source tid, then ONE fixup.
    if (tid < SPB) {
        float c[24];
        const float4* ch4 = (const float4*)(tsf + CHBASE + tid * 24);
        #pragma unroll
        for (int i = 0; i < 6; ++i) {
            float4 v = ch4[i];
            c[4 * i] = v.x; c[4 * i + 1] = v.y; c[4 * i + 2] = v.z; c[4 * i + 3] = v.w;
        }
        float a0 = c[0], a1 = c[1], a2 = c[2];
        #pragma unroll
        for (int i = 1; i < 8; ++i)
            merge33(c[3 * i], c[3 * i + 1], c[3 * i + 2], a0, a1, a2);

        // Reload this thread's source (L1/L2 hit), recompute coefficients.
        size_t gsrc = (size_t)b * NPTS + G * 256 + tid;
        const float* sp = src + gsrc * 3;
        float ax = sp[0], ay = sp[1], az = sp[2];
        f2 fx = (f2){-2.f * ax, -2.f * ax};
        f2 fy = (f2){-2.f * ay, -2.f * ay};
        f2 fz = (f2){-2.f * az, -2.f * az};

        float e0 = 3e38f, e1 = 3e38f, e2 = 3e38f;
        unsigned g0 = __float_as_uint(a0) & 127u;
        unsigned g1 = __float_as_uint(a1) & 127u;
        unsigned g2 = __float_as_uint(a2) & 127u;
        const float4* base = (const float4*)tsf;
        octet_fix(base + (g0 >> 4) * (SLOTF / 4) + (g0 & 15u) * 7, fx, fy, fz, e0, e1, e2);
        octet_fix(base + (g1 >> 4) * (SLOTF / 4) + (g1 & 15u) * 7, fx, fy, fz, e0, e1, e2);
        octet_fix(base + (g2 >> 4) * (SLOTF / 4) + (g2 & 15u) * 7, fx, fy, fz, e0, e1, e2);

        part[((size_t)Q * 3 + 0) * NSRC + gsrc] = e0;
        part[((size_t)Q * 3 + 1) * NSRC + gsrc] = e1;
        part[((size_t)Q * 3 + 2) * NSRC + gsrc] = e2;
    }
}

// Proven merge geometry (128 x 256); 24 partials per source now.
__global__ __launch_bounds__(256) void knn_merge(const float* __restrict__ src,
                                                 const float* __restrict__ part,
                                                 float* __restrict__ acc,
                                                 float* __restrict__ cnt,
                                                 unsigned* __restrict__ ticket,
                                                 float* __restrict__ out) {
    const int gid = blockIdx.x * 256 + threadIdx.x;  // 0 .. NSRC-1
    const int b = gid >> 13;                         // uniform per block

    float t0[2], t1[2], t2[2];
    #pragma unroll
    for (int c = 0; c < 2; ++c) { t0[c] = t1[c] = t2[c] = 3e38f; }
    #pragma unroll
    for (int q = 0; q < NQ * 3; ++q)
        insert3(part[(size_t)q * NSRC + gid], t0[q & 1], t1[q & 1], t2[q & 1]);
    merge33(t0[1], t1[1], t2[1], t0[0], t1[0], t2[0]);

    float sx = src[(size_t)gid * 3 + 0];
    float sy = src[(size_t)gid * 3 + 1];
    float sz = src[(size_t)gid * 3 + 2];
    bool valid = (sx != 0.f) || (sy != 0.f) || (sz != 0.f);
    float qq = sx * sx + sy * sy + sz * sz;  // deferred |s|^2
    float s = valid ? (sqrtf(fmaxf(t0[0] + qq, 0.f)) + sqrtf(fmaxf(t1[0] + qq, 0.f)) +
                       sqrtf(fmaxf(t2[0] + qq, 0.f)))
                    : 0.f;
    float c = valid ? 1.f : 0.f;

    for (int off = 32; off >= 1; off >>= 1) {
        s += __shfl_down(s, off);
        c += __shfl_down(c, off);
    }
    __shared__ float red_s[4], red_c[4];
    int wave = threadIdx.x >> 6, lane = threadIdx.x & 63;
    if (lane == 0) { red_s[wave] = s; red_c[wave] = c; }
    __syncthreads();
    if (threadIdx.x == 0) {
        atomicAdd(&acc[b], red_s[0] + red_s[1] + red_s[2] + red_s[3]);
        atomicAdd(&cnt[b], red_c[0] + red_c[1] + red_c[2] + red_c[3]);
        __threadfence();
        unsigned t = atomicAdd(ticket, 1u);
        if (t == (unsigned)(MERGE_BLOCKS - 1)) {
            float loss = 0.f;
            #pragma unroll
            for (int bb = 0; bb < BATCH; ++bb) {
                float as = atomicAdd(&acc[bb], 0.f);
                float ac = atomicAdd(&cnt[bb], 0.f);
                loss += as / (ac * 3.0f);
            }
            out[0] = loss * (1.0f / BATCH);
        }
    }
}

extern "C" void kernel_launch(void* const* d_in, const int* in_sizes, int n_in,
                              void* d_out, int out_size, void* d_ws, size_t ws_size,
                              hipStream_t stream) {
    const float* src = (const float*)d_in[0];
    const float* tgt = (const float*)d_in[1];
    float* out = (float*)d_out;

    // ws: [0,16) acc[4]; [16,32) cnt[4]; [32,36) ticket; [256,...) partials
    // partials = 8 slices x 3 x 32768 x 4B = 3.15 MB
    float* acc = (float*)d_ws;
    float* cnt = acc + 4;
    unsigned* ticket = (unsigned*)((char*)d_ws + 32);
    float* part = (float*)((char*)d_ws + 256);

    hipMemsetAsync(d_ws, 0, 64, stream);  // zero header (graph-capturable)

    dim3 g1(NQ, NG, BATCH);  // 8 x 32 x 4 = 1024 blocks x 512 threads
    knn_partial<<<g1, 512, 0, stream>>>(src, tgt, part);
    knn_merge<<<dim3(MERGE_BLOCKS), 256, 0, stream>>>(src, part, acc, cnt,
                                                      ticket, out);
}

// Round 10
// 114.566 us; speedup vs baseline: 1.1059x; 1.1059x over previous
//
#include <hip/hip_runtime.h>
#include <math.h>

// knnLoss: B=4, N=8192, k=3. Brute-force 3-NN.
// R10: kill the LDS-transpose wall + force packed fp32 math.
//   - knn_prep: one-time transpose of tgt into octet-major tw[4096][24]
//     (x8,y8,z8 per octet, 96B, float4-aligned) + zero-point sentinel 1e12.
//   - knn_partial (NQ=4 x NG=32 x B, 512 blocks x 512 thr): NO LDS staging.
//     Wave w reads its 32 octets straight from tw with wave-uniform broadcast
//     global_load_dwordx4 (L1/L2-resident, one transaction each). Hot math
//     forced to v_pk_fma_f32/v_pk_mul_f32 via inline asm (R8 counters imply
//     elementwise builtins compiled scalar: VALU-busy ~2x packed count).
//     S=4 sources/lane; octet-min selection (5-bit packed idx); per-wave
//     exact fixup gathers candidate octets from tw (divergent, L1/L2).
//     LDS = 24KB merge area only. Plain __launch_bounds__(512) — R9 lesson:
//     (512,8) forced VGPR=32 and spilled 147MB to scratch.
//   - knn_merge: 12 partials/source, proven 128x256 shape + ticket finale.
#define BATCH 4
#define NPTS 8192
#define NSRC 32768            // BATCH * NPTS
#define NQ 4                  // target slices of 2048 per batch
#define NG 32                 // source groups of 256 per batch
#define SPB 256               // sources per block (64 lanes x 4)
#define NOCTW 32              // octets per wave (256 targets)
#define NOCT_B 1024           // octets per batch
#define MERGE_BLOCKS 128

typedef __attribute__((ext_vector_type(2))) float f2;

static __device__ __forceinline__ f2 pk_fma(f2 a, f2 b, f2 c) {
    f2 d;
    asm("v_pk_fma_f32 %0, %1, %2, %3" : "=v"(d) : "v"(a), "v"(b), "v"(c));
    return d;
}
static __device__ __forceinline__ f2 pk_mul(f2 a, f2 b) {
    f2 d;
    asm("v_pk_mul_f32 %0, %1, %2" : "=v"(d) : "v"(a), "v"(b));
    return d;
}

__device__ __forceinline__ float min3f(float a, float b, float c) {
    float d;
    asm("v_min3_f32 %0, %1, %2, %3" : "=v"(d) : "v"(a), "v"(b), "v"(c));
    return d;
}

// Branchless insert into sorted ascending triple; 4 ops via med3.
__device__ __forceinline__ void insert3(float d, float& a0, float& a1, float& a2) {
    float h = fmaxf(a1, d);
    float m = __builtin_amdgcn_fmed3f(a0, a1, d);
    a2 = fminf(a2, h);
    a1 = m;
    a0 = fminf(a0, d);
}

// Merge two sorted-ascending triples -> the sorted 3 smallest of the union.
__device__ __forceinline__ void merge33(float a0, float a1, float a2,
                                        float& b0, float& b1, float& b2) {
    float s0 = fminf(a0, b0);
    float h  = fmaxf(a0, b0);
    float m  = fminf(a1, b1);
    float mm = fminf(a2, b2);
    b1 = fminf(h, m);
    b2 = __builtin_amdgcn_fmed3f(h, m, mm);
    b0 = s0;
}

// Exact recompute of one octet (6 float4s from tw, w rebuilt) -> insert.
__device__ __forceinline__ void octet_fix(const float4* ob, f2 nx, f2 ny, f2 nz,
                                          float& c0, float& c1, float& c2) {
    float4 X0 = ob[0], X1 = ob[1], Y0 = ob[2], Y1 = ob[3], Z0 = ob[4], Z1 = ob[5];
    f2 xs0 = (f2){X0.x, X0.y}, xs1 = (f2){X0.z, X0.w};
    f2 xs2 = (f2){X1.x, X1.y}, xs3 = (f2){X1.z, X1.w};
    f2 ys0 = (f2){Y0.x, Y0.y}, ys1 = (f2){Y0.z, Y0.w};
    f2 ys2 = (f2){Y1.x, Y1.y}, ys3 = (f2){Y1.z, Y1.w};
    f2 zs0 = (f2){Z0.x, Z0.y}, zs1 = (f2){Z0.z, Z0.w};
    f2 zs2 = (f2){Z1.x, Z1.y}, zs3 = (f2){Z1.z, Z1.w};
    f2 w0 = pk_mul(zs0, zs0); w0 = pk_fma(ys0, ys0, w0); w0 = pk_fma(xs0, xs0, w0);
    f2 w1 = pk_mul(zs1, zs1); w1 = pk_fma(ys1, ys1, w1); w1 = pk_fma(xs1, xs1, w1);
    f2 w2 = pk_mul(zs2, zs2); w2 = pk_fma(ys2, ys2, w2); w2 = pk_fma(xs2, xs2, w2);
    f2 w3 = pk_mul(zs3, zs3); w3 = pk_fma(ys3, ys3, w3); w3 = pk_fma(xs3, xs3, w3);
    f2 pa = pk_fma(zs0, nz, w0); pa = pk_fma(ys0, ny, pa); pa = pk_fma(xs0, nx, pa);
    f2 pb = pk_fma(zs1, nz, w1); pb = pk_fma(ys1, ny, pb); pb = pk_fma(xs1, nx, pb);
    f2 pc = pk_fma(zs2, nz, w2); pc = pk_fma(ys2, ny, pc); pc = pk_fma(xs2, nx, pc);
    f2 pd = pk_fma(zs3, nz, w3); pd = pk_fma(ys3, ny, pd); pd = pk_fma(xs3, nx, pd);
    insert3(pa.x, c0, c1, c2);
    insert3(pa.y, c0, c1, c2);
    insert3(pb.x, c0, c1, c2);
    insert3(pb.y, c0, c1, c2);
    insert3(pc.x, c0, c1, c2);
    insert3(pc.y, c0, c1, c2);
    insert3(pd.x, c0, c1, c2);
    insert3(pd.y, c0, c1, c2);
}

// One thread per octet: transpose 8 targets (xyz-interleaved) -> x8|y8|z8,
// zero-point -> 1e12 sentinel (p ~ 3e24, never top-3; reference excludes them).
__global__ __launch_bounds__(256) void knn_prep(const float* __restrict__ tgt,
                                                float* __restrict__ tw) {
    int gid = blockIdx.x * 256 + threadIdx.x;  // 0..4095
    const float4* tf = (const float4*)(tgt + (size_t)gid * 24);
    float4 f0 = tf[0], f1 = tf[1], f2v = tf[2], f3 = tf[3], f4v = tf[4], f5 = tf[5];
    float tx[8], ty[8], tz[8];
    tx[0] = f0.x;  ty[0] = f0.y;  tz[0] = f0.z;
    tx[1] = f0.w;  ty[1] = f1.x;  tz[1] = f1.y;
    tx[2] = f1.z;  ty[2] = f1.w;  tz[2] = f2v.x;
    tx[3] = f2v.y; ty[3] = f2v.z; tz[3] = f2v.w;
    tx[4] = f3.x;  ty[4] = f3.y;  tz[4] = f3.z;
    tx[5] = f3.w;  ty[5] = f4v.x; tz[5] = f4v.y;
    tx[6] = f4v.z; ty[6] = f4v.w; tz[6] = f5.x;
    tx[7] = f5.y;  ty[7] = f5.z;  tz[7] = f5.w;
    #pragma unroll
    for (int j = 0; j < 8; ++j) {
        if (!(tx[j] != 0.f || ty[j] != 0.f || tz[j] != 0.f)) {
            tx[j] = 1e12f; ty[j] = 1e12f; tz[j] = 1e12f;
        }
    }
    float4* o = (float4*)(tw + (size_t)gid * 24);
    o[0] = make_float4(tx[0], tx[1], tx[2], tx[3]);
    o[1] = make_float4(tx[4], tx[5], tx[6], tx[7]);
    o[2] = make_float4(ty[0], ty[1], ty[2], ty[3]);
    o[3] = make_float4(ty[4], ty[5], ty[6], ty[7]);
    o[4] = make_float4(tz[0], tz[1], tz[2], tz[3]);
    o[5] = make_float4(tz[4], tz[5], tz[6], tz[7]);
}

__global__ __launch_bounds__(512) void knn_partial(const float* __restrict__ src,
                                                   const float* __restrict__ tw,
                                                   float* __restrict__ part) {
    __shared__ float tsf[6144];  // 24576 B: end-of-block merge area only
    const int tid = threadIdx.x;
    const int lane = tid & 63, wave = tid >> 6;
    const int Q = blockIdx.x, G = blockIdx.y, b = blockIdx.z;

    // ---- Source precompute: lane owns 4 sources G*256 + s*64 + lane.
    f2 nx[4], ny[4], nz[4];
    #pragma unroll
    for (int s = 0; s < 4; ++s) {
        const float* sp = src + ((size_t)b * NPTS + G * 256 + s * 64 + lane) * 3;
        float ax = sp[0], ay = sp[1], az = sp[2];
        nx[s] = (f2){-2.f * ax, -2.f * ax};
        ny[s] = (f2){-2.f * ay, -2.f * ay};
        nz[s] = (f2){-2.f * az, -2.f * az};
    }

    // ---- Hot loop: 32 octets straight from tw (wave-uniform broadcast loads).
    float q0[4], q1[4], q2c[4];
    #pragma unroll
    for (int s = 0; s < 4; ++s) { q0[s] = q1[s] = q2c[s] = 3e38f; }

    const float4* tp = ((const float4*)tw) + (size_t)(b * NOCT_B + Q * 256 + wave * 32) * 6;
    #pragma unroll 4
    for (int o = 0; o < NOCTW; ++o) {
        float4 X0 = tp[6 * o + 0], X1 = tp[6 * o + 1];
        float4 Y0 = tp[6 * o + 2], Y1 = tp[6 * o + 3];
        float4 Z0 = tp[6 * o + 4], Z1 = tp[6 * o + 5];
        f2 xs0 = (f2){X0.x, X0.y}, xs1 = (f2){X0.z, X0.w};
        f2 xs2 = (f2){X1.x, X1.y}, xs3 = (f2){X1.z, X1.w};
        f2 ys0 = (f2){Y0.x, Y0.y}, ys1 = (f2){Y0.z, Y0.w};
        f2 ys2 = (f2){Y1.x, Y1.y}, ys3 = (f2){Y1.z, Y1.w};
        f2 zs0 = (f2){Z0.x, Z0.y}, zs1 = (f2){Z0.z, Z0.w};
        f2 zs2 = (f2){Z1.x, Z1.y}, zs3 = (f2){Z1.z, Z1.w};
        // w = |t|^2 once per octet, amortized over 4 sources (packed).
        f2 w0 = pk_mul(zs0, zs0); w0 = pk_fma(ys0, ys0, w0); w0 = pk_fma(xs0, xs0, w0);
        f2 w1 = pk_mul(zs1, zs1); w1 = pk_fma(ys1, ys1, w1); w1 = pk_fma(xs1, xs1, w1);
        f2 w2 = pk_mul(zs2, zs2); w2 = pk_fma(ys2, ys2, w2); w2 = pk_fma(xs2, xs2, w2);
        f2 w3 = pk_mul(zs3, zs3); w3 = pk_fma(ys3, ys3, w3); w3 = pk_fma(xs3, xs3, w3);
        #pragma unroll
        for (int s = 0; s < 4; ++s) {
            f2 pa = pk_fma(zs0, nz[s], w0); pa = pk_fma(ys0, ny[s], pa); pa = pk_fma(xs0, nx[s], pa);
            f2 pb = pk_fma(zs1, nz[s], w1); pb = pk_fma(ys1, ny[s], pb); pb = pk_fma(xs1, nx[s], pb);
            f2 pc = pk_fma(zs2, nz[s], w2); pc = pk_fma(ys2, ny[s], pc); pc = pk_fma(xs2, nx[s], pc);
            f2 pd = pk_fma(zs3, nz[s], w3); pd = pk_fma(ys3, ny[s], pd); pd = pk_fma(xs3, nx[s], pd);
            float m1 = min3f(pa.x, pa.y, pb.x);
            float m2 = min3f(pb.y, pc.x, pc.y);
            float m3 = min3f(pd.x, pd.y, m1);
            float m4 = fminf(m2, m3);
            unsigned u = (__float_as_uint(m4) & 0xFFFFFFE0u) | (unsigned)o;
            insert3(__uint_as_float(u), q0[s], q1[s], q2c[s]);
        }
    }

    // ---- Exact fixup: gather <=3 candidate octets from tw (divergent, L1/L2).
    float e0[4], e1[4], e2[4];
    #pragma unroll
    for (int s = 0; s < 4; ++s) {
        e0[s] = 3e38f; e1[s] = 3e38f; e2[s] = 3e38f;
        octet_fix(tp + 6 * (int)(__float_as_uint(q0[s]) & 31u),
                  nx[s], ny[s], nz[s], e0[s], e1[s], e2[s]);
        octet_fix(tp + 6 * (int)(__float_as_uint(q1[s]) & 31u),
                  nx[s], ny[s], nz[s], e0[s], e1[s], e2[s]);
        octet_fix(tp + 6 * (int)(__float_as_uint(q2c[s]) & 31u),
                  nx[s], ny[s], nz[s], e0[s], e1[s], e2[s]);
    }

    // ---- In-block merge across 8 waves via LDS.
    #pragma unroll
    for (int s = 0; s < 4; ++s) {
        int idx = ((s * 8 + wave) * 64 + lane) * 3;  // max 6143
        tsf[idx] = e0[s]; tsf[idx + 1] = e1[s]; tsf[idx + 2] = e2[s];
    }
    __syncthreads();

    if (tid < SPB) {
        int s = tid >> 6, l = tid & 63;
        int base = (s * 8 * 64 + l) * 3;
        float a0 = tsf[base], a1 = tsf[base + 1], a2 = tsf[base + 2];
        #pragma unroll
        for (int w = 1; w < 8; ++w) {
            int bse = ((s * 8 + w) * 64 + l) * 3;
            merge33(tsf[bse], tsf[bse + 1], tsf[bse + 2], a0, a1, a2);
        }
        size_t gsrc = (size_t)b * NPTS + G * 256 + tid;
        part[((size_t)Q * 3 + 0) * NSRC + gsrc] = a0;
        part[((size_t)Q * 3 + 1) * NSRC + gsrc] = a1;
        part[((size_t)Q * 3 + 2) * NSRC + gsrc] = a2;
    }
}

// Proven merge geometry (128 x 256); 12 partials per source.
__global__ __launch_bounds__(256) void knn_merge(const float* __restrict__ src,
                                                 const float* __restrict__ part,
                                                 float* __restrict__ acc,
                                                 float* __restrict__ cnt,
                                                 unsigned* __restrict__ ticket,
                                                 float* __restrict__ out) {
    const int gid = blockIdx.x * 256 + threadIdx.x;  // 0 .. NSRC-1
    const int b = gid >> 13;                         // uniform per block

    float t0[2], t1[2], t2[2];
    #pragma unroll
    for (int c = 0; c < 2; ++c) { t0[c] = t1[c] = t2[c] = 3e38f; }
    #pragma unroll
    for (int q = 0; q < NQ * 3; ++q)
        insert3(part[(size_t)q * NSRC + gid], t0[q & 1], t1[q & 1], t2[q & 1]);
    merge33(t0[1], t1[1], t2[1], t0[0], t1[0], t2[0]);

    float sx = src[(size_t)gid * 3 + 0];
    float sy = src[(size_t)gid * 3 + 1];
    float sz = src[(size_t)gid * 3 + 2];
    bool valid = (sx != 0.f) || (sy != 0.f) || (sz != 0.f);
    float qq = sx * sx + sy * sy + sz * sz;  // deferred |s|^2
    float s = valid ? (sqrtf(fmaxf(t0[0] + qq, 0.f)) + sqrtf(fmaxf(t1[0] + qq, 0.f)) +
                       sqrtf(fmaxf(t2[0] + qq, 0.f)))
                    : 0.f;
    float c = valid ? 1.f : 0.f;

    for (int off = 32; off >= 1; off >>= 1) {
        s += __shfl_down(s, off);
        c += __shfl_down(c, off);
    }
    __shared__ float red_s[4], red_c[4];
    int wave = threadIdx.x >> 6, lane = threadIdx.x & 63;
    if (lane == 0) { red_s[wave] = s; red_c[wave] = c; }
    __syncthreads();
    if (threadIdx.x == 0) {
        atomicAdd(&acc[b], red_s[0] + red_s[1] + red_s[2] + red_s[3]);
        atomicAdd(&cnt[b], red_c[0] + red_c[1] + red_c[2] + red_c[3]);
        __threadfence();
        unsigned t = atomicAdd(ticket, 1u);
        if (t == (unsigned)(MERGE_BLOCKS - 1)) {
            float loss = 0.f;
            #pragma unroll
            for (int bb = 0; bb < BATCH; ++bb) {
                float as = atomicAdd(&acc[bb], 0.f);
                float ac = atomicAdd(&cnt[bb], 0.f);
                loss += as / (ac * 3.0f);
            }
            out[0] = loss * (1.0f / BATCH);
        }
    }
}

extern "C" void kernel_launch(void* const* d_in, const int* in_sizes, int n_in,
                              void* d_out, int out_size, void* d_ws, size_t ws_size,
                              hipStream_t stream) {
    const float* src = (const float*)d_in[0];
    const float* tgt = (const float*)d_in[1];
    float* out = (float*)d_out;

    // ws: [0,16) acc[4]; [16,32) cnt[4]; [32,36) ticket;
    //     [256, 256+1572864) partials (4 x 3 x 32768 x 4B);
    //     [2M, 2M+393216) tw (4096 octets x 24 floats).
    float* acc = (float*)d_ws;
    float* cnt = acc + 4;
    unsigned* ticket = (unsigned*)((char*)d_ws + 32);
    float* part = (float*)((char*)d_ws + 256);
    float* tw = (float*)((char*)d_ws + (2u << 20));

    hipMemsetAsync(d_ws, 0, 64, stream);  // zero header (graph-capturable)

    knn_prep<<<dim3(16), 256, 0, stream>>>(tgt, tw);
    dim3 g1(NQ, NG, BATCH);  // 4 x 32 x 4 = 512 blocks x 512 threads
    knn_partial<<<g1, 512, 0, stream>>>(src, tw, part);
    knn_merge<<<dim3(MERGE_BLOCKS), 256, 0, stream>>>(src, part, acc, cnt,
                                                      ticket, out);
}